// Round 17
// baseline (78.669 us; speedup 1.0000x reference)
//
#include <hip/hip_runtime.h>
#include <math.h>

// One TRIPLE (view v, template point t) per LANE; 3 waves per block split the
// 120 unordered pairs (40 compile-time pairs each via template<int W>), LDS
// lex-min reduce. Each wave computes its own full prologue (16 f64 sqrts etc.)
// -- NO cross-wave sharing (round 9 showed the LDS+barrier cost cancels it).
// Why 3 waves: 1280 groups x 3 = 3840 waves <= 4096 resident slots (VGPR<=128
// -> 4 waves/SIMD) -> exactly ONE residency round, no low-occupancy tail.
// Round 8 (4 waves) = 5120 waves -> 1.25 rounds, ~6us serial-ish tail.
//
// Hot loop: 2D cross-product identity. den = (a x b)^2 = c2;
// validity {p0,p1,p2 in [0,1], den!=0} == {c2>0, u2>=0, u1>=0, rem>=0}
// with u2=(t x b)*c, u1=(a x t)*c, rem=c2-u2-u1 (<=c2 halves implied by
// sign-exact f64 subtract). Pairs touching the closest point auto-reject
// (v_ci == exact 0 -> c2 == +0). Orientation (nearer-first; tie -> smaller
// original index) applied only to the winner in the epilogue with
// bit-identically recomputed distances. Winner weights use the reference's
// Gram + 1/den rounding path. All selection semantics verified absmax 0.0
// in rounds 1/4/8/9.

template<int W>
__device__ __forceinline__ void scan_pairs(
    const float2 (&pt)[16], const double (&d)[16],
    double cx, double cy, double v2x, double v2y, double cd,
    double& best, unsigned& bkey)
{
#pragma unroll
    for (int i = 0; i < 15; ++i) {
        double vxi = (double)pt[i].x - cx, vyi = (double)pt[i].y - cy;
        double wi  = vxi * v2y - vyi * v2x;          // a x t  (DCE'd if unused)
#pragma unroll
        for (int j = i + 1; j < 16; ++j) {
            const int p = 15 * i - (i * (i - 1)) / 2 + (j - i - 1); // 0..119
            if (p < W * 40 || p >= (W + 1) * 40) continue;  // constant-folded
            double vxj = (double)pt[j].x - cx, vyj = (double)pt[j].y - cy;
            double wj  = vxj * v2y - vyj * v2x;      // = -(t x b), CSE'd per j
            double c   = vxi * vyj - vyi * vxj;      // a x b
            double c2  = c * c;                      // = Gram den (exact math)
            double u2  = -wj * c;                    // p2 * c2
            double u1  =  wi * c;                    // p1 * c2
            double rem = c2 - u2 - u1;               // p0 * c2
            bool ok = (c2 > 0.0) && (u2 >= 0.0) && (u1 >= 0.0) && (rem >= 0.0);
            double tot = (d[i] + d[j]) + cd;         // reference rounding order
            if (ok && (tot < best)) {
                best = tot;
                bkey = (unsigned)((p << 8) | (i << 4) | j);  // compile-time const
            }
        }
    }
}

__global__ __launch_bounds__(192, 4) void bc_kernel(
    const float* __restrict__ tmpl,   // (RA,2)
    const float* __restrict__ proj,   // (V,16,2)
    float* __restrict__ out,
    int RA, int total_n)
{
    __shared__ double   s_best[3][64];
    __shared__ unsigned s_key[3][64];

    int lane = threadIdx.x & 63;
    int w    = threadIdx.x / 64;            // wave id 0..2 (uniform per wave)
    int triple = blockIdx.x * 64 + lane;
    bool active = triple < total_n;
    int tr = active ? triple : 0;
    int v = tr / RA;
    int t = tr - v * RA;

    double tx = (double)tmpl[2 * t];
    double ty = (double)tmpl[2 * t + 1];

    float2 pt[16];
    const float4* pv4 = (const float4*)(proj + (size_t)v * 32);
#pragma unroll
    for (int k = 0; k < 8; ++k) {
        float4 q = pv4[k];
        pt[2 * k]     = make_float2(q.x, q.y);
        pt[2 * k + 1] = make_float2(q.z, q.w);
    }

    double d[16];
#pragma unroll
    for (int k = 0; k < 16; ++k) {
        double dx = tx - (double)pt[k].x;
        double dy = ty - (double)pt[k].y;
        d[k] = sqrt(dx * dx + dy * dy);
    }

    // argmin distance, first occurrence on exact tie (stable argsort order[0])
    int ci = 0;
    double cd = d[0];
#pragma unroll
    for (int k = 1; k < 16; ++k)
        if (d[k] < cd) { cd = d[k]; ci = k; }

    float cxf = pt[0].x, cyf = pt[0].y;
#pragma unroll
    for (int k = 1; k < 16; ++k)
        if (k == ci) { cxf = pt[k].x; cyf = pt[k].y; }
    double cx = (double)cxf, cy = (double)cyf;    // bit-copies of pt[ci]
    double v2x = tx - cx, v2y = ty - cy;

    double best = INFINITY;
    unsigned bkey = 0xFFFFFFFFu;

    if (w == 0)      scan_pairs<0>(pt, d, cx, cy, v2x, v2y, cd, best, bkey);
    else if (w == 1) scan_pairs<1>(pt, d, cx, cy, v2x, v2y, cd, best, bkey);
    else             scan_pairs<2>(pt, d, cx, cy, v2x, v2y, cd, best, bkey);

    s_best[w][lane] = best;
    s_key[w][lane]  = bkey;
    __syncthreads();

    if (w == 0 && active) {
#pragma unroll
        for (int q = 1; q < 3; ++q) {
            double   ob   = s_best[q][lane];
            unsigned okey = s_key[q][lane];
            // lexicographic (tot, enumeration-key): preserves serial first-win
            if (ob < best || (ob == best && okey < bkey)) { best = ob; bkey = okey; }
        }

        float w0 = 0.f, w1 = 0.f, w2 = 0.f;
        int i0 = 0, i1 = 0, i2 = 0;
        if (best < INFINITY) {
            int bi = (int)((bkey >> 4) & 15u);      // original order, bi < bj
            int bj = (int)(bkey & 15u);
            const float* pvf = proj + (size_t)v * 32;
            // recompute distances bit-identically to prologue d[]
            double pix = (double)pvf[2 * bi],     piy = (double)pvf[2 * bi + 1];
            double pjx = (double)pvf[2 * bj],     pjy = (double)pvf[2 * bj + 1];
            double dxi = tx - pix, dyi = ty - piy;
            double dxj = tx - pjx, dyj = ty - pjy;
            double di = sqrt(dxi * dxi + dyi * dyi);
            double dj = sqrt(dxj * dxj + dyj * dyj);
            // orient nearer-first; exact tie -> smaller original index (bi)
            bool swp = dj < di;
            double pnx = swp ? pjx : pix, pny = swp ? pjy : piy;
            double pmx = swp ? pix : pjx, pmy = swp ? piy : pjy;
            int n_idx = swp ? bj : bi,   m_idx = swp ? bi : bj;
            // reference rounding path: Gram dots + inv = 1/den
            double vxn = pnx - cx, vyn = pny - cy;
            double vxm = pmx - cx, vym = pmy - cy;
            double d00n = vxn * vxn + vyn * vyn;
            double d00m = vxm * vxm + vym * vym;
            double d01  = vxn * vxm + vyn * vym;
            double den  = d00n * d00m - d01 * d01;
            double inv  = 1.0 / den;
            double d02n = vxn * v2x + vyn * v2y;
            double d02m = vxm * v2x + vym * v2y;
            double p2 = (d02n * d00m - d01 * d02m) * inv;
            double p1 = (d00n * d02m - d01 * d02n) * inv;
            double p0 = 1.0 - p2 - p1;
            w0 = (float)p0; w1 = (float)p2; w2 = (float)p1;
            i0 = ci; i1 = n_idx; i2 = m_idx;
        }
        float* wout = out + (size_t)tr * 3;
        wout[0] = w0; wout[1] = w1; wout[2] = w2;
        float* iout = out + (size_t)total_n * 3 + (size_t)tr * 3;
        iout[0] = (float)i0; iout[1] = (float)i1; iout[2] = (float)i2;
    }
}

extern "C" void kernel_launch(void* const* d_in, const int* in_sizes, int n_in,
                              void* d_out, int out_size, void* d_ws, size_t ws_size,
                              hipStream_t stream) {
    const float* tmpl = (const float*)d_in[0];
    const float* proj = (const float*)d_in[1];
    float* out = (float*)d_out;

    int RA = in_sizes[0] / 2;          // 40
    int V  = in_sizes[1] / 32;         // 2048 (N=16 hardcoded)
    int total_n = V * RA;              // 81920

    int block = 192;                   // 3 waves x 40-pair bands
    int grid = (total_n + 63) / 64;    // 64 triples per block = 1280 blocks
    bc_kernel<<<grid, block, 0, stream>>>(tmpl, proj, out, RA, total_n);
}

// Round 19
// 69.313 us; speedup vs baseline: 1.1350x; 1.1350x over previous
//
#include <hip/hip_runtime.h>
#include <math.h>

// CHAMPION (round 8, 69.1 us harness / ~17 us kernel) — reverted after both
// w=3 variants regressed (r9: 72.4 w/ sqrt-sharing; r17: 78.7 w/ 40-pair bands
// + launch_bounds(192,4), suspected VGPR-cap spills). This config: 4 waves per
// 64-triple group, 30-pair compile-time bands, no forced VGPR cap.
//
// One TRIPLE (view v, template point t) per LANE; 4 waves per block split the
// 120 unordered pairs (30 compile-time pairs each via template<int W>), LDS
// lex-min reduce. Hot loop uses the 2D cross-product identity:
//   den = |a|^2|b|^2 - (a.b)^2 = (a x b)^2 = c2,  p2 = (t x b)/c,  p1 = (a x t)/c
// so validity {p0,p1,p2 in [0,1], den!=0} reduces to
//   c2 > 0  &&  u2 >= 0  &&  u1 >= 0  &&  rem >= 0
// with u2=(t x b)*c, u1=(a x t)*c, rem=c2-u2-u1 (<=c2 halves implied by
// sign-exact f64 subtract; pairs touching the closest point auto-reject via
// c2 == +0). Orientation (nearer-first; tie -> smaller original index) applied
// only to the winner in the epilogue with bit-identically recomputed
// distances. Winner weights use the reference's Gram + 1/den rounding path.
// Selection semantics verified absmax 0.0 in rounds 1/4/8/9/17.

template<int W>
__device__ __forceinline__ void scan_pairs(
    const float2 (&pt)[16], const double (&d)[16],
    double cx, double cy, double v2x, double v2y, double cd,
    double& best, unsigned& bkey)
{
#pragma unroll
    for (int i = 0; i < 15; ++i) {
        double vxi = (double)pt[i].x - cx, vyi = (double)pt[i].y - cy;
        double wi  = vxi * v2y - vyi * v2x;          // a x t  (DCE'd if unused)
#pragma unroll
        for (int j = i + 1; j < 16; ++j) {
            const int p = 15 * i - (i * (i - 1)) / 2 + (j - i - 1); // 0..119
            if (p < W * 30 || p >= (W + 1) * 30) continue;  // constant-folded
            double vxj = (double)pt[j].x - cx, vyj = (double)pt[j].y - cy;
            double wj  = vxj * v2y - vyj * v2x;      // = -(t x b), CSE'd per j
            double c   = vxi * vyj - vyi * vxj;      // a x b
            double c2  = c * c;                      // = Gram den (exact math)
            double u2  = -wj * c;                    // p2 * c2
            double u1  =  wi * c;                    // p1 * c2
            double rem = c2 - u2 - u1;               // p0 * c2
            bool ok = (c2 > 0.0) && (u2 >= 0.0) && (u1 >= 0.0) && (rem >= 0.0);
            double tot = (d[i] + d[j]) + cd;         // reference rounding order
            if (ok && (tot < best)) {
                best = tot;
                bkey = (unsigned)((p << 8) | (i << 4) | j);  // compile-time const
            }
        }
    }
}

__global__ __launch_bounds__(256) void bc_kernel(
    const float* __restrict__ tmpl,   // (RA,2)
    const float* __restrict__ proj,   // (V,16,2)
    float* __restrict__ out,
    int RA, int total_n)
{
    __shared__ double   s_best[4][64];
    __shared__ unsigned s_key[4][64];

    int lane = threadIdx.x & 63;
    int w    = threadIdx.x >> 6;            // wave id 0..3 (uniform per wave)
    int triple = blockIdx.x * 64 + lane;
    bool active = triple < total_n;
    int tr = active ? triple : 0;
    int v = tr / RA;
    int t = tr - v * RA;

    double tx = (double)tmpl[2 * t];
    double ty = (double)tmpl[2 * t + 1];

    float2 pt[16];
    const float4* pv4 = (const float4*)(proj + (size_t)v * 32);
#pragma unroll
    for (int k = 0; k < 8; ++k) {
        float4 q = pv4[k];
        pt[2 * k]     = make_float2(q.x, q.y);
        pt[2 * k + 1] = make_float2(q.z, q.w);
    }

    double d[16];
#pragma unroll
    for (int k = 0; k < 16; ++k) {
        double dx = tx - (double)pt[k].x;
        double dy = ty - (double)pt[k].y;
        d[k] = sqrt(dx * dx + dy * dy);
    }

    // argmin distance, first occurrence on exact tie (stable argsort order[0])
    int ci = 0;
    double cd = d[0];
#pragma unroll
    for (int k = 1; k < 16; ++k)
        if (d[k] < cd) { cd = d[k]; ci = k; }

    float cxf = pt[0].x, cyf = pt[0].y;
#pragma unroll
    for (int k = 1; k < 16; ++k)
        if (k == ci) { cxf = pt[k].x; cyf = pt[k].y; }
    double cx = (double)cxf, cy = (double)cyf;    // bit-copies of pt[ci]
    double v2x = tx - cx, v2y = ty - cy;

    double best = INFINITY;
    unsigned bkey = 0xFFFFFFFFu;

    if (w == 0)      scan_pairs<0>(pt, d, cx, cy, v2x, v2y, cd, best, bkey);
    else if (w == 1) scan_pairs<1>(pt, d, cx, cy, v2x, v2y, cd, best, bkey);
    else if (w == 2) scan_pairs<2>(pt, d, cx, cy, v2x, v2y, cd, best, bkey);
    else             scan_pairs<3>(pt, d, cx, cy, v2x, v2y, cd, best, bkey);

    s_best[w][lane] = best;
    s_key[w][lane]  = bkey;
    __syncthreads();

    if (w == 0 && active) {
#pragma unroll
        for (int q = 1; q < 4; ++q) {
            double   ob   = s_best[q][lane];
            unsigned okey = s_key[q][lane];
            // lexicographic (tot, enumeration-key): preserves serial first-win
            if (ob < best || (ob == best && okey < bkey)) { best = ob; bkey = okey; }
        }

        float w0 = 0.f, w1 = 0.f, w2 = 0.f;
        int i0 = 0, i1 = 0, i2 = 0;
        if (best < INFINITY) {
            int bi = (int)((bkey >> 4) & 15u);      // original order, bi < bj
            int bj = (int)(bkey & 15u);
            const float* pvf = proj + (size_t)v * 32;
            // recompute distances bit-identically to prologue d[]
            double pix = (double)pvf[2 * bi],     piy = (double)pvf[2 * bi + 1];
            double pjx = (double)pvf[2 * bj],     pjy = (double)pvf[2 * bj + 1];
            double dxi = tx - pix, dyi = ty - piy;
            double dxj = tx - pjx, dyj = ty - pjy;
            double di = sqrt(dxi * dxi + dyi * dyi);
            double dj = sqrt(dxj * dxj + dyj * dyj);
            // orient nearer-first; exact tie -> smaller original index (bi)
            bool swp = dj < di;
            double pnx = swp ? pjx : pix, pny = swp ? pjy : piy;
            double pmx = swp ? pix : pjx, pmy = swp ? piy : pjy;
            int n_idx = swp ? bj : bi,   m_idx = swp ? bi : bj;
            // reference rounding path: Gram dots + inv = 1/den
            double vxn = pnx - cx, vyn = pny - cy;
            double vxm = pmx - cx, vym = pmy - cy;
            double d00n = vxn * vxn + vyn * vyn;
            double d00m = vxm * vxm + vym * vym;
            double d01  = vxn * vxm + vyn * vym;
            double den  = d00n * d00m - d01 * d01;
            double inv  = 1.0 / den;
            double d02n = vxn * v2x + vyn * v2y;
            double d02m = vxm * v2x + vym * v2y;
            double p2 = (d02n * d00m - d01 * d02m) * inv;
            double p1 = (d00n * d02m - d01 * d02n) * inv;
            double p0 = 1.0 - p2 - p1;
            w0 = (float)p0; w1 = (float)p2; w2 = (float)p1;
            i0 = ci; i1 = n_idx; i2 = m_idx;
        }
        float* wout = out + (size_t)tr * 3;
        wout[0] = w0; wout[1] = w1; wout[2] = w2;
        float* iout = out + (size_t)total_n * 3 + (size_t)tr * 3;
        iout[0] = (float)i0; iout[1] = (float)i1; iout[2] = (float)i2;
    }
}

extern "C" void kernel_launch(void* const* d_in, const int* in_sizes, int n_in,
                              void* d_out, int out_size, void* d_ws, size_t ws_size,
                              hipStream_t stream) {
    const float* tmpl = (const float*)d_in[0];
    const float* proj = (const float*)d_in[1];
    float* out = (float*)d_out;

    int RA = in_sizes[0] / 2;          // 40
    int V  = in_sizes[1] / 32;         // 2048 (N=16 hardcoded)
    int total_n = V * RA;              // 81920

    int block = 256;                   // 4 waves: 30-pair bands
    int grid = (total_n + 63) / 64;    // 64 triples per block = 1280 blocks
    bc_kernel<<<grid, block, 0, stream>>>(tmpl, proj, out, RA, total_n);
}